// Round 3
// baseline (270.562 us; speedup 1.0000x reference)
//
#include <hip/hip_runtime.h>
#include <hip/hip_bf16.h>
#include <stdint.h>

typedef __hip_bfloat16 bf16;
typedef short v8s __attribute__((ext_vector_type(8)));
typedef float v4f __attribute__((ext_vector_type(4)));

// Shape fixed by setup_inputs: B=4, T=2048, D=1024, H=16, hd=64, n=1024.
#define TT   2048
#define DD   1024
#define HH   16
#define HDIM 64
#define NN   1024
#define MASKV (-1e9f)
// q scale = hd^-0.5 * log2(e): softmax p = exp2(score) == e^{qk/sqrt(hd)}
#define QSCALE 0.18033688011112042f

#if __has_builtin(__builtin_amdgcn_exp2f)
#define EXP2F(x) __builtin_amdgcn_exp2f(x)
#else
#define EXP2F(x) exp2f(x)
#endif

__device__ __forceinline__ v4f mfma16x16x32(v8s a, v8s b, v4f c) {
    return __builtin_amdgcn_mfma_f32_16x16x32_bf16(a, b, c, 0, 0, 0);
}

#define GLDS16(lds, g)                                                          \
    __builtin_amdgcn_global_load_lds(                                           \
        (const __attribute__((address_space(1))) void*)(g),                     \
        (__attribute__((address_space(3))) void*)(lds), 16, 0, 0)

__device__ __forceinline__ bf16 f2b(float f) { return __float2bfloat16(f); }

// ---------------------------------------------------------------------------
// x (fp32, 8192x1024) -> bf16
// ---------------------------------------------------------------------------
__global__ __launch_bounds__(256) void cast_x(const float* __restrict__ x,
                                              bf16* __restrict__ xb)
{
    const size_t i = ((size_t)blockIdx.x * 256 + threadIdx.x) * 4;
    const float4 f = *(const float4*)(x + i);
    union { bf16 b[4]; uint64_t u; } cv;
    cv.b[0] = f2b(f.x); cv.b[1] = f2b(f.y); cv.b[2] = f2b(f.z); cv.b[3] = f2b(f.w);
    *(uint64_t*)(xb + i) = cv.u;
}

// ---------------------------------------------------------------------------
// Transpose+cast 4x (1024x1024) fp32 weights -> bf16 dst[z*1M + n*1024 + k]
// ---------------------------------------------------------------------------
__global__ __launch_bounds__(256) void transpose_w(
    const float* __restrict__ w0, const float* __restrict__ w1,
    const float* __restrict__ w2, const float* __restrict__ w3,
    bf16* __restrict__ dst)
{
    __shared__ float tile[64][65];
    const float* src = (blockIdx.z == 0) ? w0 : (blockIdx.z == 1) ? w1
                      : (blockIdx.z == 2) ? w2 : w3;
    bf16* d = dst + (size_t)blockIdx.z * 1024 * 1024;
    const int r0 = blockIdx.y * 64, c0 = blockIdx.x * 64;
    const int tx = threadIdx.x, ty = threadIdx.y;
#pragma unroll
    for (int j = 0; j < 16; j++) {
        int r = ty + j * 4;
        tile[r][tx] = src[(size_t)(r0 + r) * 1024 + c0 + tx];
    }
    __syncthreads();
#pragma unroll
    for (int j = 0; j < 16; j++) {
        int r = ty + j * 4;
        d[(size_t)(c0 + r) * 1024 + r0 + tx] = f2b(tile[tx][r]);
    }
}

// ---------------------------------------------------------------------------
// V transpose per (b,h): vtmp[bh][t][d] -> vt[bh][d][t]
// ---------------------------------------------------------------------------
__global__ __launch_bounds__(256) void transpose_v(
    const bf16* __restrict__ vtmp, bf16* __restrict__ vt)
{
    __shared__ bf16 tile[64][66];
    const int bh = blockIdx.y, t0 = blockIdx.x * 64;
    const int tx = threadIdx.x, ty = threadIdx.y;
    const bf16* src = vtmp + (size_t)bh * TT * HDIM;
    bf16* dst = vt + (size_t)bh * HDIM * TT;
#pragma unroll
    for (int j = 0; j < 16; j++) {
        int r = ty + j * 4;
        tile[r][tx] = src[(size_t)(t0 + r) * HDIM + tx];
    }
    __syncthreads();
#pragma unroll
    for (int j = 0; j < 16; j++) {
        int r = ty + j * 4;
        dst[(size_t)r * TT + t0 + tx] = tile[tx][r];
    }
}

// ---------------------------------------------------------------------------
// Shared 256x(64*NB)x1024 bf16 GEMM core. 512 thr = 8 waves as 4M x 2N,
// per-wave C = 64 x (NB*32+...): wm = wv>>1 owns 64 rows, wn = wv&1 owns
// NB*32 cols. 4 mt-phases per K-tile (BK=64), 2*NB MFMA-pairs per phase.
//
// A LDS is mt-interleaved: staging call j holds, for every wm-block, its
// 16 rows {wm*64 + j*16 + 0..15} at lds rows {j*64 + wm*16 + ..}. So phase
// p depends ONLY on A-call p -> deep counted-vmcnt pipeline.
// B LDS linear (call j = rows 64j..); B frags read ONCE per K-tile at P0
// and reused by all 4 phases (MFMA:ds_read = 48:20 for NB=3).
//
// ONE barrier per phase (4/tile, was 8). Safety: the only cross-wave hazard
// is DMA-write vs ds_read on the same buffer; buffers alternate per tile
// and s_barrier releases only when ALL waves arrived, i.e. all finished
// their MFMA (and thus their lgkm-waited ds_reads) for the phase. A wave
// entering tile t+1 therefore cannot overwrite data a peer still reads.
//
// Pipeline, calls/tile = NB+4, issue sets per phase (for next tile):
//   NB=3: I0={b0,b1} I1={b2,a0} I2={a1,a2} I3={a3}; needs: P0:{b*,a0},
//         P1:a1, P2:a2, P3:a3 -> waits vmcnt(4)/(5)/(6)/(3).
//   NB=2: I0={b0,b1} I1={a0,a1} I2={a2} I3={a3} -> vmcnt(4)/(5)/(5)/(3).
// Min 3 loads in flight; never drained in-loop. Tail restages itself into
// the dead buffer (ktn clamp) to keep counts uniform.
// ---------------------------------------------------------------------------
template<int NB>
__device__ __forceinline__ void gemm_core_mt(
    const bf16* __restrict__ A, const bf16* __restrict__ BT,
    const int m0, const int n0,
    bf16* __restrict__ As, bf16* __restrict__ Bs,
    v4f (&acc)[4][2 * NB])
{
    constexpr int K = 1024, NT = K >> 6, NTS = 2 * NB;
    constexpr int BHALF = NB * 64 * 64;               // B elems per dbuf half
    const int tid  = threadIdx.x;
    const int lane = tid & 63, wv = tid >> 6;
    const int quad = lane >> 4, c = lane & 15;
    const int wm = wv >> 1, wn = wv & 1;
    const int c7 = c & 7;

    // DMA lane mapping: lds row rr = wv*8 + (lane>>3); granule lane&7,
    // source granule pre-XORed by rr&7 (= lane>>3) so linear-dest DMA
    // yields the read-side XOR layout.
    const int q8 = lane >> 3, rr = wv * 8 + q8;
    const int gsw = ((lane & 7) ^ q8) << 3;
    // A source: call j, lds row rr holds global row (rr>>4)*64 + j*16 + (rr&15)
    const bf16* aSrc = A  + (size_t)(m0 + (rr >> 4) * 64 + (rr & 15)) * K + gsw;
    const bf16* bSrc = BT + (size_t)(n0 + rr) * K + gsw;

    auto stageA = [&](bf16* dst, int j, int kt) {
        GLDS16(dst + (j * 64 + wv * 8) * 64, aSrc + (size_t)(j * 16) * K + kt * 64);
    };
    auto stageB = [&](bf16* dst, int j, int kt) {
        GLDS16(dst + (j * 64 + wv * 8) * 64, bSrc + (size_t)(j * 64) * K + kt * 64);
    };

#pragma unroll
    for (int i = 0; i < 4; i++)
#pragma unroll
        for (int j = 0; j < NTS; j++) acc[i][j] = (v4f){0.f, 0.f, 0.f, 0.f};

    // ---- prologue: tile 0, need-order b*,a0..a3; leave 3 in flight -------
#pragma unroll
    for (int j = 0; j < NB; j++) stageB(Bs, j, 0);
#pragma unroll
    for (int j = 0; j < 4; j++)  stageA(As, j, 0);
    asm volatile("s_waitcnt vmcnt(3)" ::: "memory");
    asm volatile("s_barrier" ::: "memory");

#pragma unroll 1
    for (int kt = 0; kt < NT; ++kt) {
        bf16* Ac = As + (kt & 1) * 16384;
        bf16* Bc = Bs + (kt & 1) * BHALF;
        bf16* An = As + ((kt & 1) ^ 1) * 16384;
        bf16* Bn = Bs + ((kt & 1) ^ 1) * BHALF;
        const int ktn = (kt + 1 < NT) ? kt + 1 : kt;   // tail: dummy restage

        // -------- P0 (mt=0): read all B frags + A0, 2*NTS MFMA ------------
        stageB(Bn, 0, ktn); stageB(Bn, 1, ktn);
        v8s bfr[NTS][2];
#pragma unroll
        for (int nt = 0; nt < NTS; nt++)
#pragma unroll
            for (int kh = 0; kh < 2; kh++)
                bfr[nt][kh] = *(const v8s*)(Bc + (wn * (NB * 32) + nt * 16 + c) * 64
                                            + (((kh * 4 + quad) ^ c7) << 3));
        v8s af0, af1;
        af0 = *(const v8s*)(Ac + (0 * 64 + wm * 16 + c) * 64 + (((0 + quad) ^ c7) << 3));
        af1 = *(const v8s*)(Ac + (0 * 64 + wm * 16 + c) * 64 + (((4 + quad) ^ c7) << 3));
        __builtin_amdgcn_s_setprio(1);
#pragma unroll
        for (int nt = 0; nt < NTS; nt++) {
            acc[0][nt] = mfma16x16x32(af0, bfr[nt][0], acc[0][nt]);
            acc[0][nt] = mfma16x16x32(af1, bfr[nt][1], acc[0][nt]);
        }
        __builtin_amdgcn_s_setprio(0);
        asm volatile("s_waitcnt vmcnt(4)" ::: "memory");
        asm volatile("s_barrier" ::: "memory");

        // -------- P1 (mt=1) ----------------------------------------------
        if constexpr (NB == 3) { stageB(Bn, 2, ktn); stageA(An, 0, ktn); }
        else                   { stageA(An, 0, ktn); stageA(An, 1, ktn); }
        af0 = *(const v8s*)(Ac + (1 * 64 + wm * 16 + c) * 64 + (((0 + quad) ^ c7) << 3));
        af1 = *(const v8s*)(Ac + (1 * 64 + wm * 16 + c) * 64 + (((4 + quad) ^ c7) << 3));
        __builtin_amdgcn_s_setprio(1);
#pragma unroll
        for (int nt = 0; nt < NTS; nt++) {
            acc[1][nt] = mfma16x16x32(af0, bfr[nt][0], acc[1][nt]);
            acc[1][nt] = mfma16x16x32(af1, bfr[nt][1], acc[1][nt]);
        }
        __builtin_amdgcn_s_setprio(0);
        asm volatile("s_waitcnt vmcnt(5)" ::: "memory");
        asm volatile("s_barrier" ::: "memory");

        // -------- P2 (mt=2) ----------------------------------------------
        if constexpr (NB == 3) { stageA(An, 1, ktn); stageA(An, 2, ktn); }
        else                   { stageA(An, 2, ktn); }
        af0 = *(const v8s*)(Ac + (2 * 64 + wm * 16 + c) * 64 + (((0 + quad) ^ c7) << 3));
        af1 = *(const v8s*)(Ac + (2 * 64 + wm * 16 + c) * 64 + (((4 + quad) ^ c7) << 3));
        __builtin_amdgcn_s_setprio(1);
#pragma unroll
        for (int nt = 0; nt < NTS; nt++) {
            acc[2][nt] = mfma16x16x32(af0, bfr[nt][0], acc[2][nt]);
            acc[2][nt] = mfma16x16x32(af1, bfr[nt][1], acc[2][nt]);
        }
        __builtin_amdgcn_s_setprio(0);
        if constexpr (NB == 3)
            asm volatile("s_waitcnt vmcnt(6)" ::: "memory");
        else
            asm volatile("s_waitcnt vmcnt(5)" ::: "memory");
        asm volatile("s_barrier" ::: "memory");

        // -------- P3 (mt=3) ----------------------------------------------
        stageA(An, 3, ktn);
        af0 = *(const v8s*)(Ac + (3 * 64 + wm * 16 + c) * 64 + (((0 + quad) ^ c7) << 3));
        af1 = *(const v8s*)(Ac + (3 * 64 + wm * 16 + c) * 64 + (((4 + quad) ^ c7) << 3));
        __builtin_amdgcn_s_setprio(1);
#pragma unroll
        for (int nt = 0; nt < NTS; nt++) {
            acc[3][nt] = mfma16x16x32(af0, bfr[nt][0], acc[3][nt]);
            acc[3][nt] = mfma16x16x32(af1, bfr[nt][1], acc[3][nt]);
        }
        __builtin_amdgcn_s_setprio(0);
        asm volatile("s_waitcnt vmcnt(3)" ::: "memory");
        asm volatile("s_barrier" ::: "memory");
    }
    asm volatile("s_waitcnt vmcnt(0)" ::: "memory");   // drain tail dummies
}

// ---------------------------------------------------------------------------
// QKV GEMM: C = xb(8192x1024) * wqkvT(3072x1024)^T, tile 256x192x64.
// Grid 512 = 32x16 = exactly 2 full rounds; bijective XCD swizzle.
// ---------------------------------------------------------------------------
__global__ __launch_bounds__(512, 2) void gemm_qkv(
    const bf16* __restrict__ A, const bf16* __restrict__ BT,
    const float* __restrict__ bq, const float* __restrict__ bk,
    const float* __restrict__ bv,
    bf16* __restrict__ qo, bf16* __restrict__ ko, bf16* __restrict__ vo)
{
    __shared__ __align__(16) bf16 As[2 * 256 * 64];   // 64 KB
    __shared__ __align__(16) bf16 Bs[2 * 192 * 64];   // 48 KB
    const int id  = blockIdx.x;
    const int fid = (id & 7) * 64 + (id >> 3);        // XCD-contiguous chunks
    const int by  = fid >> 4, bx = fid & 15;          // bx fastest: share A
    const int m0  = by * 256, n0 = bx * 192;

    v4f acc[4][6];
    gemm_core_mt<3>(A, BT, m0, n0, As, Bs, acc);

    const int tid  = threadIdx.x;
    const int lane = tid & 63, wv = tid >> 6;
    const int quad = lane >> 4, c = lane & 15;
    const int wm = wv >> 1, wn = wv & 1;

#pragma unroll
    for (int p = 0; p < 4; p++)
#pragma unroll
        for (int nt = 0; nt < 6; nt++) {
            const int colb = n0 + wn * 96 + nt * 16;
            const int type = colb >> 10;
            bf16* o = (type == 0) ? qo : (type == 1) ? ko : vo;
            const float* bp = (type == 0) ? bq : (type == 1) ? bk : bv;
            const float scale = (type == 0) ? QSCALE : 1.0f;
            const int within = (colb & 1023) + c;
            const int h = within >> 6, d = within & 63;
            const float bias = bp[within];
#pragma unroll
            for (int r = 0; r < 4; r++) {
                const int row = m0 + wm * 64 + p * 16 + quad * 4 + r;
                const int b_ = row >> 11, t = row & 2047;
                const int bh = b_ * HH + h;
                o[((size_t)bh * TT + t) * HDIM + d] =
                    f2b((acc[p][nt][r] + bias) * scale);
            }
        }
}

// ---------------------------------------------------------------------------
// Output GEMM: out = ctx(8192x1024) * woT(1024x1024)^T + bo, fp32 out.
// Tile 256x128, grid 256 = 32x8: exactly one block per CU.
// ---------------------------------------------------------------------------
__global__ __launch_bounds__(512, 2) void gemm_out(
    const bf16* __restrict__ A, const bf16* __restrict__ BT,
    const float* __restrict__ bo, float* __restrict__ out)
{
    __shared__ __align__(16) bf16 As[2 * 256 * 64];   // 64 KB
    __shared__ __align__(16) bf16 Bs[2 * 128 * 64];   // 32 KB
    const int id  = blockIdx.x;
    const int fid = (id & 7) * 32 + (id >> 3);
    const int by  = fid >> 3, bx = fid & 7;
    const int m0  = by * 256, n0 = bx * 128;

    v4f acc[4][4];
    gemm_core_mt<2>(A, BT, m0, n0, As, Bs, acc);

    const int tid  = threadIdx.x;
    const int lane = tid & 63, wv = tid >> 6;
    const int quad = lane >> 4, c = lane & 15;
    const int wm = wv >> 1, wn = wv & 1;

#pragma unroll
    for (int p = 0; p < 4; p++)
#pragma unroll
        for (int nt = 0; nt < 4; nt++) {
            const int col = n0 + wn * 64 + nt * 16 + c;
            const float bias = bo[col];
#pragma unroll
            for (int r = 0; r < 4; r++) {
                const int row = m0 + wm * 64 + p * 16 + quad * 4 + r;
                out[(size_t)row * 1024 + col] = acc[p][nt][r] + bias;
            }
        }
}

// ---------------------------------------------------------------------------
// Flash attention v6: v5's DMA pipeline + distribution-robust load balance
// + single LDS wait per chunk + quad-XOR P layout.
// ---------------------------------------------------------------------------
__global__ __launch_bounds__(256, 4) void attn(
    const bf16* __restrict__ Q, const bf16* __restrict__ Kb,
    const bf16* __restrict__ VT, bf16* __restrict__ ctx,
    const int* __restrict__ bsp)
{
    __shared__ __align__(16) bf16 Kt[2][32 * 64];
    __shared__ __align__(16) bf16 Vt[2][64 * 32];
    __shared__ __align__(16) bf16 plds[4][2][16 * 32];

    const int bs = bsp[0];
    const float inv  = 1.0f / (float)bs;
    const float hinv = 0.5f * inv;
    const int tid = threadIdx.x, lane = tid & 63, wv = tid >> 6;
    const int quad = lane >> 4, c = lane & 15;
    const int bh = blockIdx.x & 63;
    const int j  = blockIdx.x >> 6;                // 0..15
    const int g_tbl[16] = {7,6,5,4, 0,1,2,3, 4,5,6,7, 3,2,1,0};
    const bool xt = j < 8;
    const int g  = g_tbl[j];
    const int q0g = (xt ? 0 : NN) + g * 128;

    const bf16* qp = Q  + (size_t)bh * TT * HDIM;
    const bf16* kp = Kb + (size_t)bh * TT * HDIM;
    const bf16* vp = VT + (size_t)bh * HDIM * TT;

    int d_lo = 0, nd = 0, nf = 0, b_lo = 0, nb = 0;
    if (xt) {
        d_lo = (bs * (q0g / bs)) & ~31;
        const int d_hi = min((bs * ((q0g + 127) / bs) + bs + 31) & ~31, NN);
        nd = (d_hi - d_lo) >> 5;
        const int f = bs * (q0g / bs);
        nf = f >> 5;
        b_lo = NN + (nf << 5);
        const int b_hi = NN + min((bs * ((q0g + 127) / bs) + 31) & ~31, NN);
        nb = (b_hi > b_lo) ? (b_hi - b_lo) >> 5 : 0;
    } else {
        const int q0l = q0g - NN;
        const int f = min(bs * (q0l / bs) + bs, NN);
        nf = f >> 5;
        b_lo = NN + (nf << 5);
        const int b_hi = NN + min((bs * ((q0l + 127) / bs) + bs + 31) & ~31, NN);
        nb = (b_hi > b_lo) ? (b_hi - b_lo) >> 5 : 0;
    }
    const int nc = nd + nf + nb;

    float bqv[2][4];
#pragma unroll
    for (int t = 0; t < 2; t++)
#pragma unroll
        for (int r = 0; r < 4; r++) {
            const int qrow = q0g + wv * 32 + t * 16 + quad * 4 + r;
            const int qloc = xt ? qrow : qrow - NN;
            bqv[t][r] = floorf(fmaf((float)qloc, inv, hinv));
        }

    v8s aq[2][2];
#pragma unroll
    for (int t = 0; t < 2; t++) {
        const int rowb = q0g + wv * 32 + t * 16;
        aq[t][0] = *(const v8s*)(qp + (size_t)(rowb + c) * HDIM + quad * 8);
        aq[t][1] = *(const v8s*)(qp + (size_t)(rowb + c) * HDIM + 32 + quad * 8);
    }

    v4f O[2][4];
#pragma unroll
    for (int t = 0; t < 2; t++)
#pragma unroll
        for (int dt = 0; dt < 4; dt++) O[t][dt] = (v4f){0.f, 0.f, 0.f, 0.f};
    float lr[2][4] = {{0.f,0.f,0.f,0.f},{0.f,0.f,0.f,0.f}};

    const int klrow = lane >> 3, ks8 = lane & 7;
    const bf16* kSrc0 = kp + (size_t)(wv * 8 + klrow) * HDIM + ((ks8 ^ klrow) << 3);
    const int vlrow = lane >> 2, vs8 = lane & 3;
    const bf16* vSrc0 = vp + (size_t)(wv * 16 + vlrow) * TT + ((vs8 ^ (vlrow & 3)) << 3);

    auto kb_of = [&](int i, int& kb, int& type) {
        if (i < nd)           { kb = d_lo + (i << 5);             type = 1; }
        else if (i < nd + nf) { kb = NN + ((i - nd) << 5);        type = 0; }
        else                  { kb = b_lo + ((i - nd - nf) << 5); type = xt ? 2 : 3; }
    };
    auto stage = [&](int i) {
        int kb, ty; kb_of(i, kb, ty);
        const int sel = i & 1;
        GLDS16(&Kt[sel][wv * 512], kSrc0 + (size_t)kb * HDIM);
        GLDS16(&Vt[sel][wv * 512], vSrc0 + kb);
    };

    stage(0);
    asm volatile("s_waitcnt vmcnt(0)" ::: "memory");
    asm volatile("s_barrier" ::: "memory");

    const int xk = c & 7, xv = c & 3;
    const int pquad = quad << 3;
#pragma unroll 1
    for (int i = 0; i < nc; i++) {
        int kb, type; kb_of(i, kb, type);
        const int sel = i & 1;
        const bf16* Kl = Kt[sel];
        const bf16* Vl = Vt[sel];

        const v8s k0a = *(const v8s*)(Kl + c * 64        + ((quad       ^ xk) << 3));
        const v8s k0b = *(const v8s*)(Kl + c * 64        + (((quad ^ 4) ^ xk) << 3));
        const v8s k1a = *(const v8s*)(Kl + (16 + c) * 64 + ((quad       ^ xk) << 3));
        const v8s k1b = *(const v8s*)(Kl + (16 + c) * 64 + (((quad ^ 4) ^ xk) << 3));
        v8s vf[4];
#pragma unroll
        for (int dt = 0; dt < 4; dt++)
            vf[dt] = *(const v8s*)(Vl + (dt * 16 + c) * 32 + ((quad ^ xv) << 3));

        if (i + 1 < nc) stage(i + 1);

        float bkA = 0.f, bkB = 0.f;
        if (type) {
            const int off = (type == 1) ? 0 : NN;
            bkA = floorf(fmaf((float)(kb + c - off),      inv, hinv));
            bkB = floorf(fmaf((float)(kb + 16 + c - off), inv, hinv));
        }

#pragma unroll
        for (int t = 0; t < 2; t++) {
            v4f Sa = (v4f){0.f, 0.f, 0.f, 0.f};
            v4f Sb = (v4f){0.f, 0.f, 0.f, 0.f};
            Sa = mfma16x16x32(aq[t][0], k0a, Sa);
            Sa = mfma16x16x32(aq[t][1], k0b, Sa);
            Sb = mfma16x16x32(aq[t][0], k1a, Sb);
            Sb = mfma16x16x32(aq[t][1], k1b, Sb);
            bf16* pw = &plds[wv][t][(quad * 4) * 32];
#pragma unroll
            for (int r = 0; r < 4; r++) {
                float sa = Sa[r], sb = Sb[r];
                if (type == 1) {
                    if (bkA != bqv[t][r]) sa = MASKV;
                    if (bkB != bqv[t][r]) sb = MASKV;
                } else if (type == 2) {
                    if (!(bkA < bqv[t][r])) sa = MASKV;
                    if (!(bkB < bqv[t][r])) sb = MASKV;
                } else if (type == 3) {
                    if (!(bkA <= bqv[t][r])) sa = MASKV;
                    if (!(bkB <= bqv[t][r])) sb = MASKV;
                }
                const float pa = EXP2F(sa);
                const float pb = EXP2F(sb);
                lr[t][r] += pa + pb;
                pw[r * 32 + (c ^ pquad)]        = f2b(pa);
                pw[r * 32 + ((c + 16) ^ pquad)] = f2b(pb);
            }
        }
        asm volatile("s_waitcnt lgkmcnt(0)" ::: "memory");
#pragma unroll
        for (int t = 0; t < 2; t++) {
            const v8s pf = *(const v8s*)(&plds[wv][t][c * 32 +
                                        ((quad ^ ((c >> 2) & 3)) << 3)]);
#pragma unroll
            for (int dt = 0; dt < 4; dt++)
                O[t][dt] = mfma16x16x32(pf, vf[dt], O[t][dt]);
        }

        asm volatile("s_waitcnt vmcnt(0)" ::: "memory");
        asm volatile("s_barrier" ::: "memory");
    }

    const int b_ = bh >> 4, h = bh & 15;
#pragma unroll
    for (int t = 0; t < 2; t++)
#pragma unroll
        for (int r = 0; r < 4; r++) {
            float s = lr[t][r];
#pragma unroll
            for (int off = 1; off < 16; off <<= 1) s += __shfl_xor(s, off);
            const float invl = 1.0f / fmaxf(s, 1e-30f);
            const int trow = q0g + wv * 32 + t * 16 + quad * 4 + r;
#pragma unroll
            for (int dt = 0; dt < 4; dt++)
                ctx[((size_t)(b_ * TT + trow)) * DD + h * 64 + dt * 16 + c] =
                    f2b(O[t][dt][r] * invl);
        }
}

// ---------------------------------------------------------------------------
extern "C" void kernel_launch(void* const* d_in, const int* in_sizes, int n_in,
                              void* d_out, int out_size, void* d_ws, size_t ws_size,
                              hipStream_t stream)
{
    const float* x  = (const float*)d_in[0];
    const float* Wq = (const float*)d_in[1];
    const float* bq = (const float*)d_in[2];
    const float* Wk = (const float*)d_in[3];
    const float* bk = (const float*)d_in[4];
    const float* Wv = (const float*)d_in[5];
    const float* bv = (const float*)d_in[6];
    const float* Wo = (const float*)d_in[7];
    const float* bo = (const float*)d_in[8];
    const int*  bsp = (const int*)d_in[9];
    float* out = (float*)d_out;

    bf16* ws    = (bf16*)d_ws;
    bf16* xb    = ws;                           // reused as ctx after gemm_qkv
    bf16* wqkvT = xb + 8388608;
    bf16* woT   = wqkvT + 3 * 1024 * 1024;
    bf16* qbuf  = woT + 1024 * 1024;            // (bh,t,d)
    bf16* kbuf  = qbuf + 8388608;
    bf16* vtmp  = kbuf + 8388608;               // (bh,t,d)
    bf16* vt    = vtmp + 8388608;               // (bh,d,t)
    bf16* ctx   = xb;

    cast_x<<<8192, 256, 0, stream>>>(x, xb);
    transpose_w<<<dim3(16, 16, 4), dim3(64, 4), 0, stream>>>(Wq, Wk, Wv, Wo, wqkvT);
    gemm_qkv<<<512, 512, 0, stream>>>(xb, wqkvT, bq, bk, bv, qbuf, kbuf, vtmp);
    transpose_v<<<dim3(32, 64), dim3(64, 4), 0, stream>>>(vtmp, vt);
    attn<<<1024, 256, 0, stream>>>(qbuf, kbuf, vt, ctx, bsp);
    gemm_out<<<256, 512, 0, stream>>>(ctx, woT, bo, out);
}

// Round 4
// 242.092 us; speedup vs baseline: 1.1176x; 1.1176x over previous
//
#include <hip/hip_runtime.h>
#include <hip/hip_bf16.h>
#include <stdint.h>

typedef __hip_bfloat16 bf16;
typedef short v8s __attribute__((ext_vector_type(8)));
typedef float v4f __attribute__((ext_vector_type(4)));

// Shape fixed by setup_inputs: B=4, T=2048, D=1024, H=16, hd=64, n=1024.
#define TT   2048
#define DD   1024
#define HH   16
#define HDIM 64
#define NN   1024
#define MASKV (-1e9f)
// q scale = hd^-0.5 * log2(e): softmax p = exp2(score) == e^{qk/sqrt(hd)}
#define QSCALE 0.18033688011112042f

#if __has_builtin(__builtin_amdgcn_exp2f)
#define EXP2F(x) __builtin_amdgcn_exp2f(x)
#else
#define EXP2F(x) exp2f(x)
#endif

__device__ __forceinline__ v4f mfma16x16x32(v8s a, v8s b, v4f c) {
    return __builtin_amdgcn_mfma_f32_16x16x32_bf16(a, b, c, 0, 0, 0);
}

#define GLDS16(lds, g)                                                          \
    __builtin_amdgcn_global_load_lds(                                           \
        (const __attribute__((address_space(1))) void*)(g),                     \
        (__attribute__((address_space(3))) void*)(lds), 16, 0, 0)

__device__ __forceinline__ bf16 f2b(float f) { return __float2bfloat16(f); }

// ---------------------------------------------------------------------------
// x (fp32, 8192x1024) -> bf16
// ---------------------------------------------------------------------------
__global__ __launch_bounds__(256) void cast_x(const float* __restrict__ x,
                                              bf16* __restrict__ xb)
{
    const size_t i = ((size_t)blockIdx.x * 256 + threadIdx.x) * 4;
    const float4 f = *(const float4*)(x + i);
    union { bf16 b[4]; uint64_t u; } cv;
    cv.b[0] = f2b(f.x); cv.b[1] = f2b(f.y); cv.b[2] = f2b(f.z); cv.b[3] = f2b(f.w);
    *(uint64_t*)(xb + i) = cv.u;
}

// ---------------------------------------------------------------------------
// Transpose+cast 4x (1024x1024) fp32 weights -> bf16 dst[z*1M + n*1024 + k]
// ---------------------------------------------------------------------------
__global__ __launch_bounds__(256) void transpose_w(
    const float* __restrict__ w0, const float* __restrict__ w1,
    const float* __restrict__ w2, const float* __restrict__ w3,
    bf16* __restrict__ dst)
{
    __shared__ float tile[64][65];
    const float* src = (blockIdx.z == 0) ? w0 : (blockIdx.z == 1) ? w1
                      : (blockIdx.z == 2) ? w2 : w3;
    bf16* d = dst + (size_t)blockIdx.z * 1024 * 1024;
    const int r0 = blockIdx.y * 64, c0 = blockIdx.x * 64;
    const int tx = threadIdx.x, ty = threadIdx.y;
#pragma unroll
    for (int j = 0; j < 16; j++) {
        int r = ty + j * 4;
        tile[r][tx] = src[(size_t)(r0 + r) * 1024 + c0 + tx];
    }
    __syncthreads();
#pragma unroll
    for (int j = 0; j < 16; j++) {
        int r = ty + j * 4;
        d[(size_t)(c0 + r) * 1024 + r0 + tx] = f2b(tile[tx][r]);
    }
}

// ---------------------------------------------------------------------------
// QKV GEMM: C = xb(8192x1024) * wqkvT(3072x1024)^T, tile 256x192x64.
// Proven r2 core (68.5 us): 4 phases/K-tile, 2 barriers/phase, counted vmcnt
// (3)/(4)/none/(3), granule XOR swizzle via pre-swizzled DMA source.
// NEW: V-type fragments written directly transposed to vt[bh][d][t] as
// packed 8B stores (kills the transpose_v kernel).
// ---------------------------------------------------------------------------
__global__ __launch_bounds__(512, 2) void gemm_qkv(
    const bf16* __restrict__ A, const bf16* __restrict__ BT,
    const float* __restrict__ bq, const float* __restrict__ bk,
    const float* __restrict__ bv,
    bf16* __restrict__ qo, bf16* __restrict__ ko, bf16* __restrict__ vt)
{
    __shared__ __align__(16) bf16 As[2 * 256 * 64];   // 64 KB
    __shared__ __align__(16) bf16 Bs[2 * 192 * 64];   // 48 KB
    const int K = 1024, NT = K >> 6;

    const int id  = blockIdx.x;
    const int fid = (id & 7) * 64 + (id >> 3);        // XCD-contiguous chunks
    const int by  = fid >> 4, bx = fid & 15;          // bx fastest: share A
    const int m0  = by * 256, n0 = bx * 192;

    const int tid  = threadIdx.x;
    const int lane = tid & 63, wv = tid >> 6;
    const int quad = lane >> 4, c = lane & 15;
    const int wm = wv >> 2, wn = wv & 3;
    const int c7 = c & 7;

    // ---- DMA bases: lane -> (row lane>>3, granule lane&7), source granule
    // pre-swizzled so linear-dest DMA yields the read-side XOR layout.
    const int q8  = lane >> 3;
    const int gsw = ((lane & 7) ^ (q8 & 7)) << 3;
    const bf16* aSrc = A + (size_t)(m0 + wv * 8 + q8) * K + gsw;
    const int vB = wv * 8 + q8;                        // 0..63
    const bf16* bSrc = BT + (size_t)(n0 + (vB >> 4) * 48 + (vB & 15)) * K + gsw;

    auto stageA = [&](bf16* dst, int j, int kt) {
        GLDS16(dst + (j * 64 + wv * 8) * 64, aSrc + (size_t)(j * 64) * K + kt * 64);
    };
    auto stageB = [&](bf16* dst, int j, int kt) {
        GLDS16(dst + (j * 64 + wv * 8) * 64, bSrc + (size_t)(j * 16) * K + kt * 64);
    };

    v4f acc[8][3];
#pragma unroll
    for (int i = 0; i < 8; i++)
#pragma unroll
        for (int j = 0; j < 3; j++) acc[i][j] = (v4f){0.f, 0.f, 0.f, 0.f};

    // ---- prologue: tile 0, consumption-threshold order -------------------
    stageB(Bs, 0, 0); stageB(Bs, 1, 0);
    stageA(As, 0, 0); stageA(As, 2, 0);
    stageA(As, 1, 0); stageA(As, 3, 0);
    stageB(Bs, 2, 0);
    asm volatile("s_waitcnt vmcnt(3)" ::: "memory");
    asm volatile("s_barrier" ::: "memory");

    v8s afr[4][2], bfr01[2][2], bfr2[2];
#pragma unroll 1
    for (int kt = 0; kt < NT; ++kt) {
        bf16* Ac = As + (kt & 1) * 16384;
        bf16* Bc = Bs + (kt & 1) * 12288;
        bf16* An = As + ((kt & 1) ^ 1) * 16384;
        bf16* Bn = Bs + ((kt & 1) ^ 1) * 12288;
        const int ktn = (kt + 1 < NT) ? kt + 1 : kt;   // tail: dummy restage

        // -------- P0: (mh=0, nt=0..1), 16 MFMA ----------------------------
#pragma unroll
        for (int nt = 0; nt < 2; nt++)
#pragma unroll
            for (int kh = 0; kh < 2; kh++)
                bfr01[nt][kh] = *(const v8s*)(Bc + (nt * 64 + wn * 16 + c) * 64
                                              + (((kh * 4 + quad) ^ c7) << 3));
#pragma unroll
        for (int mt = 0; mt < 4; mt++)
#pragma unroll
            for (int kh = 0; kh < 2; kh++)
                afr[mt][kh] = *(const v8s*)(Ac + (wm * 128 + mt * 16 + c) * 64
                                            + (((kh * 4 + quad) ^ c7) << 3));
        stageB(Bn, 0, ktn); stageB(Bn, 1, ktn);
        asm volatile("s_barrier" ::: "memory");
        __builtin_amdgcn_s_setprio(1);
#pragma unroll
        for (int mt = 0; mt < 4; mt++)
#pragma unroll
            for (int nt = 0; nt < 2; nt++) {
                acc[mt][nt] = mfma16x16x32(afr[mt][0], bfr01[nt][0], acc[mt][nt]);
                acc[mt][nt] = mfma16x16x32(afr[mt][1], bfr01[nt][1], acc[mt][nt]);
            }
        __builtin_amdgcn_s_setprio(0);
        asm volatile("s_waitcnt vmcnt(3)" ::: "memory");
        asm volatile("s_barrier" ::: "memory");

        // -------- P1: (mh=1, nt=0..1), 16 MFMA ----------------------------
#pragma unroll
        for (int mt = 0; mt < 4; mt++)
#pragma unroll
            for (int kh = 0; kh < 2; kh++)
                afr[mt][kh] = *(const v8s*)(Ac + (wm * 128 + 64 + mt * 16 + c) * 64
                                            + (((kh * 4 + quad) ^ c7) << 3));
        stageA(An, 0, ktn); stageA(An, 2, ktn);
        asm volatile("s_barrier" ::: "memory");
        __builtin_amdgcn_s_setprio(1);
#pragma unroll
        for (int mt = 0; mt < 4; mt++)
#pragma unroll
            for (int nt = 0; nt < 2; nt++) {
                acc[4 + mt][nt] = mfma16x16x32(afr[mt][0], bfr01[nt][0], acc[4 + mt][nt]);
                acc[4 + mt][nt] = mfma16x16x32(afr[mt][1], bfr01[nt][1], acc[4 + mt][nt]);
            }
        __builtin_amdgcn_s_setprio(0);
        asm volatile("s_waitcnt vmcnt(4)" ::: "memory");
        asm volatile("s_barrier" ::: "memory");

        // -------- P2: (mh=1, nt=2), 8 MFMA (afr reused) -------------------
#pragma unroll
        for (int kh = 0; kh < 2; kh++)
            bfr2[kh] = *(const v8s*)(Bc + (128 + wn * 16 + c) * 64
                                     + (((kh * 4 + quad) ^ c7) << 3));
        stageA(An, 1, ktn); stageA(An, 3, ktn);
        asm volatile("s_barrier" ::: "memory");
        __builtin_amdgcn_s_setprio(1);
#pragma unroll
        for (int mt = 0; mt < 4; mt++) {
            acc[4 + mt][2] = mfma16x16x32(afr[mt][0], bfr2[0], acc[4 + mt][2]);
            acc[4 + mt][2] = mfma16x16x32(afr[mt][1], bfr2[1], acc[4 + mt][2]);
        }
        __builtin_amdgcn_s_setprio(0);
        asm volatile("s_barrier" ::: "memory");

        // -------- P3: (mh=0, nt=2), 8 MFMA (bfr2 reused) ------------------
#pragma unroll
        for (int mt = 0; mt < 4; mt++)
#pragma unroll
            for (int kh = 0; kh < 2; kh++)
                afr[mt][kh] = *(const v8s*)(Ac + (wm * 128 + mt * 16 + c) * 64
                                            + (((kh * 4 + quad) ^ c7) << 3));
        stageB(Bn, 2, ktn);
        asm volatile("s_barrier" ::: "memory");
        __builtin_amdgcn_s_setprio(1);
#pragma unroll
        for (int mt = 0; mt < 4; mt++) {
            acc[mt][2] = mfma16x16x32(afr[mt][0], bfr2[0], acc[mt][2]);
            acc[mt][2] = mfma16x16x32(afr[mt][1], bfr2[1], acc[mt][2]);
        }
        __builtin_amdgcn_s_setprio(0);
        asm volatile("s_waitcnt vmcnt(3)" ::: "memory");
        asm volatile("s_barrier" ::: "memory");
    }

    // ---- epilogue: type (q/k/v) uniform per 16-wide fragment --------------
    // q/k: scalar stores to (bh,t,d). v: packed 8B stores DIRECTLY to
    // vt[bh][d][t] (4 consecutive t per thread) -- replaces transpose_v.
#pragma unroll
    for (int i = 0; i < 8; i++)
#pragma unroll
        for (int nt = 0; nt < 3; nt++) {
            const int colb = n0 + wn * 48 + nt * 16;
            const int type = colb >> 10;
            const int within = (colb & 1023) + c;
            const int h = within >> 6, d = within & 63;
            const int row0 = m0 + wm * 128 + (i >> 2) * 64 + (i & 3) * 16
                             + quad * 4;
            const int b_ = row0 >> 11, t0 = row0 & 2047;
            const int bh = b_ * HH + h;
            if (type < 2) {
                bf16* o = (type == 0) ? qo : ko;
                const float* bp = (type == 0) ? bq : bk;
                const float scale = (type == 0) ? QSCALE : 1.0f;
                const float bias = bp[within];
#pragma unroll
                for (int r = 0; r < 4; r++)
                    o[((size_t)bh * TT + (t0 + r)) * HDIM + d] =
                        f2b((acc[i][nt][r] + bias) * scale);
            } else {
                const float bias = bv[within];
                union { bf16 b[4]; uint64_t u; } cv;
#pragma unroll
                for (int r = 0; r < 4; r++) cv.b[r] = f2b(acc[i][nt][r] + bias);
                *(uint64_t*)(vt + ((size_t)bh * HDIM + d) * TT + t0) = cv.u;
            }
        }
}

// ---------------------------------------------------------------------------
// Shared 256x128x(K) bf16 GEMM mainloop (proven r2 core, kept for gemm_out).
// ---------------------------------------------------------------------------
__device__ __forceinline__ void gemm_core_256x128(
    const bf16* __restrict__ A, const bf16* __restrict__ BT,
    const int m0, const int n0, const int K,
    bf16* __restrict__ As, bf16* __restrict__ Bs,
    v4f (&acc)[8][2])
{
    const int tid  = threadIdx.x;
    const int lane = tid & 63, wv = tid >> 6;
    const int quad = lane >> 4, c = lane & 15;
    const int wm = wv >> 2, wn = wv & 3;
    const int c7 = c & 7;
    const int NT = K >> 6;

    const int rloc = wv * 8 + (lane >> 3);
    const int gsw  = ((lane & 7) ^ ((lane >> 3) & 7)) << 3;
    const bf16* aSrc = A  + (size_t)(m0 + rloc) * K + gsw;
    const bf16* bSrc = BT + (size_t)(n0 + rloc) * K + gsw;

#pragma unroll
    for (int i = 0; i < 8; i++)
#pragma unroll
        for (int j = 0; j < 2; j++) acc[i][j] = (v4f){0.f, 0.f, 0.f, 0.f};

    auto stageA = [&](bf16* dst, int j, int kt) {
        const int mo = ((j & 1) << 7) | ((j >> 1) << 6);
        GLDS16(dst + (j * 64 + wv * 8) * 64, aSrc + (size_t)mo * K + kt * 64);
    };
    auto stageB = [&](bf16* dst, int j, int kt) {
        GLDS16(dst + (j * 64 + wv * 8) * 64, bSrc + (size_t)(j << 6) * K + kt * 64);
    };

    stageB(Bs, 0, 0); stageB(Bs, 1, 0);
    stageA(As, 0, 0); stageA(As, 1, 0); stageA(As, 2, 0); stageA(As, 3, 0);
    asm volatile("s_waitcnt vmcnt(2)" ::: "memory");
    asm volatile("s_barrier" ::: "memory");

#pragma unroll 1
    for (int kt = 0; kt < NT; ++kt) {
        bf16* Ac = As + (kt & 1) * 16384;
        bf16* Bc = Bs + (kt & 1) * 8192;
        bf16* An = As + ((kt & 1) ^ 1) * 16384;
        bf16* Bn = Bs + ((kt & 1) ^ 1) * 8192;
        const int ktn = (kt + 1 < NT) ? kt + 1 : kt;

        v8s bfr[2][2];
#pragma unroll
        for (int nt = 0; nt < 2; nt++)
#pragma unroll
            for (int kh = 0; kh < 2; kh++)
                bfr[nt][kh] = *(const v8s*)(Bc + (wn * 32 + nt * 16 + c) * 64
                                            + (((kh * 4 + quad) ^ c7) << 3));
        v8s af[4][2];
#pragma unroll
        for (int mt = 0; mt < 4; mt++)
#pragma unroll
            for (int kh = 0; kh < 2; kh++)
                af[mt][kh] = *(const v8s*)(Ac + (wm * 64 + mt * 16 + c) * 64
                                           + (((kh * 4 + quad) ^ c7) << 3));
        stageB(Bn, 0, ktn); stageB(Bn, 1, ktn); stageA(An, 0, ktn);
        asm volatile("s_barrier" ::: "memory");
        __builtin_amdgcn_s_setprio(1);
#pragma unroll
        for (int mt = 0; mt < 4; mt++)
#pragma unroll
            for (int nt = 0; nt < 2; nt++) {
                acc[mt][nt] = mfma16x16x32(af[mt][0], bfr[nt][0], acc[mt][nt]);
                acc[mt][nt] = mfma16x16x32(af[mt][1], bfr[nt][1], acc[mt][nt]);
            }
        __builtin_amdgcn_s_setprio(0);
        asm volatile("s_waitcnt vmcnt(3)" ::: "memory");
        asm volatile("s_barrier" ::: "memory");

#pragma unroll
        for (int mt = 0; mt < 4; mt++)
#pragma unroll
            for (int kh = 0; kh < 2; kh++)
                af[mt][kh] = *(const v8s*)(Ac + (128 + wm * 64 + mt * 16 + c) * 64
                                           + (((kh * 4 + quad) ^ c7) << 3));
        stageA(An, 1, ktn); stageA(An, 2, ktn); stageA(An, 3, ktn);
        asm volatile("s_barrier" ::: "memory");
        __builtin_amdgcn_s_setprio(1);
#pragma unroll
        for (int mt = 0; mt < 4; mt++)
#pragma unroll
            for (int nt = 0; nt < 2; nt++) {
                acc[4 + mt][nt] = mfma16x16x32(af[mt][0], bfr[nt][0], acc[4 + mt][nt]);
                acc[4 + mt][nt] = mfma16x16x32(af[mt][1], bfr[nt][1], acc[4 + mt][nt]);
            }
        __builtin_amdgcn_s_setprio(0);
        asm volatile("s_waitcnt vmcnt(2)" ::: "memory");
        asm volatile("s_barrier" ::: "memory");
    }
}

// ---------------------------------------------------------------------------
// Output GEMM: out = ctx(8192x1024) * woT(1024x1024)^T + bo, fp32 out.
// Grid 256 = 32x8: exactly one block per CU.
// ---------------------------------------------------------------------------
__global__ __launch_bounds__(512, 2) void gemm_out(
    const bf16* __restrict__ A, const bf16* __restrict__ BT,
    const float* __restrict__ bo, float* __restrict__ out)
{
    __shared__ __align__(16) bf16 As[2 * 256 * 64];
    __shared__ __align__(16) bf16 Bs[2 * 128 * 64];
    const int id  = blockIdx.x;
    const int fid = (id & 7) * 32 + (id >> 3);
    const int by  = fid >> 3, bx = fid & 7;
    const int m0  = by * 256, n0 = bx * 128;

    v4f acc[8][2];
    gemm_core_256x128(A, BT, m0, n0, 1024, As, Bs, acc);

    const int tid  = threadIdx.x;
    const int lane = tid & 63, wv = tid >> 6;
    const int quad = lane >> 4, c = lane & 15;
    const int wm = wv >> 2, wn = wv & 3;

#pragma unroll
    for (int mt = 0; mt < 8; mt++)
#pragma unroll
        for (int nt = 0; nt < 2; nt++) {
            const int col = n0 + wn * 32 + nt * 16 + c;
            const float bias = bo[col];
#pragma unroll
            for (int r = 0; r < 4; r++) {
                const int row = m0 + wm * 128 + mt * 16 + quad * 4 + r;
                out[(size_t)row * 1024 + col] = acc[mt][nt][r] + bias;
            }
        }
}

// ---------------------------------------------------------------------------
// Flash attention v7: v6 + depth-2 DMA pipeline (3 LDS buffers, counted
// vmcnt(2) instead of the per-chunk vmcnt(0) full drain).
// Per chunk i: reads slot i%3; stages chunk i+2 into slot (i+2)%3 (the slot
// chunk i-1 just finished); end-of-chunk vmcnt(2) guarantees chunk i+1's
// K/V landed while i+2's 2 calls stay in flight. Tail chunks dummy-restage
// nc-1 into the dead slot to keep the count uniform.
// LDS 32 KB/block -> still 4 blocks/CU (128 <= 160 KB).
// ---------------------------------------------------------------------------
__global__ __launch_bounds__(256, 4) void attn(
    const bf16* __restrict__ Q, const bf16* __restrict__ Kb,
    const bf16* __restrict__ VT, bf16* __restrict__ ctx,
    const int* __restrict__ bsp)
{
    __shared__ __align__(16) bf16 Kt[3][32 * 64];
    __shared__ __align__(16) bf16 Vt[3][64 * 32];
    __shared__ __align__(16) bf16 plds[4][2][16 * 32];

    const int bs = bsp[0];
    const float inv  = 1.0f / (float)bs;
    const float hinv = 0.5f * inv;
    const int tid = threadIdx.x, lane = tid & 63, wv = tid >> 6;
    const int quad = lane >> 4, c = lane & 15;
    const int bh = blockIdx.x & 63;
    const int j  = blockIdx.x >> 6;                // 0..15
    const int g_tbl[16] = {7,6,5,4, 0,1,2,3, 4,5,6,7, 3,2,1,0};
    const bool xt = j < 8;
    const int g  = g_tbl[j];
    const int q0g = (xt ? 0 : NN) + g * 128;

    const bf16* qp = Q  + (size_t)bh * TT * HDIM;
    const bf16* kp = Kb + (size_t)bh * TT * HDIM;
    const bf16* vp = VT + (size_t)bh * HDIM * TT;

    int d_lo = 0, nd = 0, nf = 0, b_lo = 0, nb = 0;
    if (xt) {
        d_lo = (bs * (q0g / bs)) & ~31;
        const int d_hi = min((bs * ((q0g + 127) / bs) + bs + 31) & ~31, NN);
        nd = (d_hi - d_lo) >> 5;
        const int f = bs * (q0g / bs);
        nf = f >> 5;
        b_lo = NN + (nf << 5);
        const int b_hi = NN + min((bs * ((q0g + 127) / bs) + 31) & ~31, NN);
        nb = (b_hi > b_lo) ? (b_hi - b_lo) >> 5 : 0;
    } else {
        const int q0l = q0g - NN;
        const int f = min(bs * (q0l / bs) + bs, NN);
        nf = f >> 5;
        b_lo = NN + (nf << 5);
        const int b_hi = NN + min((bs * ((q0l + 127) / bs) + bs + 31) & ~31, NN);
        nb = (b_hi > b_lo) ? (b_hi - b_lo) >> 5 : 0;
    }
    const int nc = nd + nf + nb;

    float bqv[2][4];
#pragma unroll
    for (int t = 0; t < 2; t++)
#pragma unroll
        for (int r = 0; r < 4; r++) {
            const int qrow = q0g + wv * 32 + t * 16 + quad * 4 + r;
            const int qloc = xt ? qrow : qrow - NN;
            bqv[t][r] = floorf(fmaf((float)qloc, inv, hinv));
        }

    v8s aq[2][2];
#pragma unroll
    for (int t = 0; t < 2; t++) {
        const int rowb = q0g + wv * 32 + t * 16;
        aq[t][0] = *(const v8s*)(qp + (size_t)(rowb + c) * HDIM + quad * 8);
        aq[t][1] = *(const v8s*)(qp + (size_t)(rowb + c) * HDIM + 32 + quad * 8);
    }

    v4f O[2][4];
#pragma unroll
    for (int t = 0; t < 2; t++)
#pragma unroll
        for (int dt = 0; dt < 4; dt++) O[t][dt] = (v4f){0.f, 0.f, 0.f, 0.f};
    float lr[2][4] = {{0.f,0.f,0.f,0.f},{0.f,0.f,0.f,0.f}};

    const int klrow = lane >> 3, ks8 = lane & 7;
    const bf16* kSrc0 = kp + (size_t)(wv * 8 + klrow) * HDIM + ((ks8 ^ klrow) << 3);
    const int vlrow = lane >> 2, vs8 = lane & 3;
    const bf16* vSrc0 = vp + (size_t)(wv * 16 + vlrow) * TT + ((vs8 ^ (vlrow & 3)) << 3);

    auto kb_of = [&](int i, int& kb, int& type) {
        if (i < nd)           { kb = d_lo + (i << 5);             type = 1; }
        else if (i < nd + nf) { kb = NN + ((i - nd) << 5);        type = 0; }
        else                  { kb = b_lo + ((i - nd - nf) << 5); type = xt ? 2 : 3; }
    };
    auto stage = [&](int ch, int slot) {
        int kb, ty; kb_of(ch, kb, ty);
        GLDS16(&Kt[slot][wv * 512], kSrc0 + (size_t)kb * HDIM);
        GLDS16(&Vt[slot][wv * 512], vSrc0 + kb);
    };

    // ---- prologue: chunks 0,1 in flight; wait only for chunk 0 -----------
    stage(0, 0);
    stage(nc > 1 ? 1 : 0, 1);
    asm volatile("s_waitcnt vmcnt(2)" ::: "memory");
    asm volatile("s_barrier" ::: "memory");

    const int xk = c & 7, xv = c & 3;
    const int pquad = quad << 3;
    int sel = 0;
#pragma unroll 1
    for (int i = 0; i < nc; i++) {
        int kb, type; kb_of(i, kb, type);
        const bf16* Kl = Kt[sel];
        const bf16* Vl = Vt[sel];

        const v8s k0a = *(const v8s*)(Kl + c * 64        + ((quad       ^ xk) << 3));
        const v8s k0b = *(const v8s*)(Kl + c * 64        + (((quad ^ 4) ^ xk) << 3));
        const v8s k1a = *(const v8s*)(Kl + (16 + c) * 64 + ((quad       ^ xk) << 3));
        const v8s k1b = *(const v8s*)(Kl + (16 + c) * 64 + (((quad ^ 4) ^ xk) << 3));
        v8s vf[4];
#pragma unroll
        for (int dt = 0; dt < 4; dt++)
            vf[dt] = *(const v8s*)(Vl + (dt * 16 + c) * 32 + ((quad ^ xv) << 3));

        // depth-2 prefetch into the slot chunk i-1 just vacated
        const int selp2 = (sel >= 1) ? sel - 1 : 2;       // (sel+2)%3
        stage(i + 2 < nc ? i + 2 : nc - 1, selp2);

        float bkA = 0.f, bkB = 0.f;
        if (type) {
            const int off = (type == 1) ? 0 : NN;
            bkA = floorf(fmaf((float)(kb + c - off),      inv, hinv));
            bkB = floorf(fmaf((float)(kb + 16 + c - off), inv, hinv));
        }

#pragma unroll
        for (int t = 0; t < 2; t++) {
            v4f Sa = (v4f){0.f, 0.f, 0.f, 0.f};
            v4f Sb = (v4f){0.f, 0.f, 0.f, 0.f};
            Sa = mfma16x16x32(aq[t][0], k0a, Sa);
            Sa = mfma16x16x32(aq[t][1], k0b, Sa);
            Sb = mfma16x16x32(aq[t][0], k1a, Sb);
            Sb = mfma16x16x32(aq[t][1], k1b, Sb);
            bf16* pw = &plds[wv][t][(quad * 4) * 32];
#pragma unroll
            for (int r = 0; r < 4; r++) {
                float sa = Sa[r], sb = Sb[r];
                if (type == 1) {
                    if (bkA != bqv[t][r]) sa = MASKV;
                    if (bkB != bqv[t][r]) sb = MASKV;
                } else if (type == 2) {
                    if (!(bkA < bqv[t][r])) sa = MASKV;
                    if (!(bkB < bqv[t][r])) sb = MASKV;
                } else if (type == 3) {
                    if (!(bkA <= bqv[t][r])) sa = MASKV;
                    if (!(bkB <= bqv[t][r])) sb = MASKV;
                }
                const float pa = EXP2F(sa);
                const float pb = EXP2F(sb);
                lr[t][r] += pa + pb;
                pw[r * 32 + (c ^ pquad)]        = f2b(pa);
                pw[r * 32 + ((c + 16) ^ pquad)] = f2b(pb);
            }
        }
        asm volatile("s_waitcnt lgkmcnt(0)" ::: "memory");
#pragma unroll
        for (int t = 0; t < 2; t++) {
            const v8s pf = *(const v8s*)(&plds[wv][t][c * 32 +
                                        ((quad ^ ((c >> 2) & 3)) << 3)]);
#pragma unroll
            for (int dt = 0; dt < 4; dt++)
                O[t][dt] = mfma16x16x32(pf, vf[dt], O[t][dt]);
        }

        // counted wait: chunk i+1's K/V landed; i+2's 2 calls stay in flight
        asm volatile("s_waitcnt vmcnt(2)" ::: "memory");
        asm volatile("s_barrier" ::: "memory");
        sel = (sel >= 2) ? 0 : sel + 1;
    }

    const int b_ = bh >> 4, h = bh & 15;
#pragma unroll
    for (int t = 0; t < 2; t++)
#pragma unroll
        for (int r = 0; r < 4; r++) {
            float s = lr[t][r];
#pragma unroll
            for (int off = 1; off < 16; off <<= 1) s += __shfl_xor(s, off);
            const float invl = 1.0f / fmaxf(s, 1e-30f);
            const int trow = q0g + wv * 32 + t * 16 + quad * 4 + r;
#pragma unroll
            for (int dt = 0; dt < 4; dt++)
                ctx[((size_t)(b_ * TT + trow)) * DD + h * 64 + dt * 16 + c] =
                    f2b(O[t][dt][r] * invl);
        }
}

// ---------------------------------------------------------------------------
extern "C" void kernel_launch(void* const* d_in, const int* in_sizes, int n_in,
                              void* d_out, int out_size, void* d_ws, size_t ws_size,
                              hipStream_t stream)
{
    const float* x  = (const float*)d_in[0];
    const float* Wq = (const float*)d_in[1];
    const float* bq = (const float*)d_in[2];
    const float* Wk = (const float*)d_in[3];
    const float* bk = (const float*)d_in[4];
    const float* Wv = (const float*)d_in[5];
    const float* bv = (const float*)d_in[6];
    const float* Wo = (const float*)d_in[7];
    const float* bo = (const float*)d_in[8];
    const int*  bsp = (const int*)d_in[9];
    float* out = (float*)d_out;

    bf16* ws    = (bf16*)d_ws;
    bf16* xb    = ws;                           // reused as ctx after gemm_qkv
    bf16* wqkvT = xb + 8388608;
    bf16* woT   = wqkvT + 3 * 1024 * 1024;
    bf16* qbuf  = woT + 1024 * 1024;            // (bh,t,d)
    bf16* kbuf  = qbuf + 8388608;
    bf16* vt    = kbuf + 8388608;               // (bh,d,t) written by gemm_qkv
    bf16* ctx   = xb;

    cast_x<<<8192, 256, 0, stream>>>(x, xb);
    transpose_w<<<dim3(16, 16, 4), dim3(64, 4), 0, stream>>>(Wq, Wk, Wv, Wo, wqkvT);
    gemm_qkv<<<512, 512, 0, stream>>>(xb, wqkvT, bq, bk, bv, qbuf, kbuf, vt);
    attn<<<1024, 256, 0, stream>>>(qbuf, kbuf, vt, ctx, bsp);
    gemm_out<<<256, 512, 0, stream>>>(ctx, woT, bo, out);
}

// Round 5
// 238.740 us; speedup vs baseline: 1.1333x; 1.0140x over previous
//
#include <hip/hip_runtime.h>
#include <hip/hip_bf16.h>
#include <stdint.h>

typedef __hip_bfloat16 bf16;
typedef short v8s __attribute__((ext_vector_type(8)));
typedef float v4f __attribute__((ext_vector_type(4)));

// Shape fixed by setup_inputs: B=4, T=2048, D=1024, H=16, hd=64, n=1024.
#define TT   2048
#define DD   1024
#define HH   16
#define HDIM 64
#define NN   1024
#define MASKV (-1e9f)
// q scale = hd^-0.5 * log2(e): softmax p = exp2(score) == e^{qk/sqrt(hd)}
#define QSCALE 0.18033688011112042f

#if __has_builtin(__builtin_amdgcn_exp2f)
#define EXP2F(x) __builtin_amdgcn_exp2f(x)
#else
#define EXP2F(x) exp2f(x)
#endif

__device__ __forceinline__ v4f mfma16x16x32(v8s a, v8s b, v4f c) {
    return __builtin_amdgcn_mfma_f32_16x16x32_bf16(a, b, c, 0, 0, 0);
}

// SW=true swaps operands: computes C^T in-register (lane col = A-row = t).
// A- and B-fragments share the same lane layout (lane&15 = non-K dim,
// quad*8+j = K slice), so the swap is layout-free.
template<bool SW>
__device__ __forceinline__ v4f MM(v8s a, v8s b, v4f c) {
    if constexpr (SW)
        return __builtin_amdgcn_mfma_f32_16x16x32_bf16(b, a, c, 0, 0, 0);
    else
        return __builtin_amdgcn_mfma_f32_16x16x32_bf16(a, b, c, 0, 0, 0);
}

#define GLDS16(lds, g)                                                          \
    __builtin_amdgcn_global_load_lds(                                           \
        (const __attribute__((address_space(1))) void*)(g),                     \
        (__attribute__((address_space(3))) void*)(lds), 16, 0, 0)

__device__ __forceinline__ bf16 f2b(float f) { return __float2bfloat16(f); }

// ---------------------------------------------------------------------------
// x (fp32, 8192x1024) -> bf16
// ---------------------------------------------------------------------------
__global__ __launch_bounds__(256) void cast_x(const float* __restrict__ x,
                                              bf16* __restrict__ xb)
{
    const size_t i = ((size_t)blockIdx.x * 256 + threadIdx.x) * 4;
    const float4 f = *(const float4*)(x + i);
    union { bf16 b[4]; uint64_t u; } cv;
    cv.b[0] = f2b(f.x); cv.b[1] = f2b(f.y); cv.b[2] = f2b(f.z); cv.b[3] = f2b(f.w);
    *(uint64_t*)(xb + i) = cv.u;
}

// ---------------------------------------------------------------------------
// Transpose+cast 4x (1024x1024) fp32 weights -> bf16 dst[z*1M + n*1024 + k]
// ---------------------------------------------------------------------------
__global__ __launch_bounds__(256) void transpose_w(
    const float* __restrict__ w0, const float* __restrict__ w1,
    const float* __restrict__ w2, const float* __restrict__ w3,
    bf16* __restrict__ dst)
{
    __shared__ float tile[64][65];
    const float* src = (blockIdx.z == 0) ? w0 : (blockIdx.z == 1) ? w1
                      : (blockIdx.z == 2) ? w2 : w3;
    bf16* d = dst + (size_t)blockIdx.z * 1024 * 1024;
    const int r0 = blockIdx.y * 64, c0 = blockIdx.x * 64;
    const int tx = threadIdx.x, ty = threadIdx.y;
#pragma unroll
    for (int j = 0; j < 16; j++) {
        int r = ty + j * 4;
        tile[r][tx] = src[(size_t)(r0 + r) * 1024 + c0 + tx];
    }
    __syncthreads();
#pragma unroll
    for (int j = 0; j < 16; j++) {
        int r = ty + j * 4;
        d[(size_t)(c0 + r) * 1024 + r0 + tx] = f2b(tile[tx][r]);
    }
}

// ---------------------------------------------------------------------------
// Shared 256x128x(K) bf16 GEMM mainloop (r1-proven: 69.3 us in qkv context).
// 512 thr = 8 waves (2M x 4N), 4 phases/K-tile, 2 barriers/phase, counted
// vmcnt; A staged mh-permuted (call j -> global rows ((j&1)<<7)|((j>>1)<<6)),
// granule XOR swizzle applied via pre-swizzled DMA global source.
// SW=true: all MFMAs operand-swapped -> acc holds C^T fragments.
// ---------------------------------------------------------------------------
template<bool SW>
__device__ __forceinline__ void gemm_core_256x128(
    const bf16* __restrict__ A, const bf16* __restrict__ BT,
    const int m0, const int n0, const int K,
    bf16* __restrict__ As, bf16* __restrict__ Bs,
    v4f (&acc)[8][2])
{
    const int tid  = threadIdx.x;
    const int lane = tid & 63, wv = tid >> 6;
    const int quad = lane >> 4, c = lane & 15;
    const int wm = wv >> 2, wn = wv & 3;
    const int c7 = c & 7;
    const int NT = K >> 6;

    const int rloc = wv * 8 + (lane >> 3);
    const int gsw  = ((lane & 7) ^ ((lane >> 3) & 7)) << 3;
    const bf16* aSrc = A  + (size_t)(m0 + rloc) * K + gsw;
    const bf16* bSrc = BT + (size_t)(n0 + rloc) * K + gsw;

#pragma unroll
    for (int i = 0; i < 8; i++)
#pragma unroll
        for (int j = 0; j < 2; j++) acc[i][j] = (v4f){0.f, 0.f, 0.f, 0.f};

    auto stageA = [&](bf16* dst, int j, int kt) {
        const int mo = ((j & 1) << 7) | ((j >> 1) << 6);
        GLDS16(dst + (j * 64 + wv * 8) * 64, aSrc + (size_t)mo * K + kt * 64);
    };
    auto stageB = [&](bf16* dst, int j, int kt) {
        GLDS16(dst + (j * 64 + wv * 8) * 64, bSrc + (size_t)(j << 6) * K + kt * 64);
    };

    stageB(Bs, 0, 0); stageB(Bs, 1, 0);
    stageA(As, 0, 0); stageA(As, 1, 0); stageA(As, 2, 0); stageA(As, 3, 0);
    asm volatile("s_waitcnt vmcnt(2)" ::: "memory");
    asm volatile("s_barrier" ::: "memory");

#pragma unroll 1
    for (int kt = 0; kt < NT; ++kt) {
        bf16* Ac = As + (kt & 1) * 16384;
        bf16* Bc = Bs + (kt & 1) * 8192;
        bf16* An = As + ((kt & 1) ^ 1) * 16384;
        bf16* Bn = Bs + ((kt & 1) ^ 1) * 8192;
        const int ktn = (kt + 1 < NT) ? kt + 1 : kt;

        v8s bfr[2][2];
#pragma unroll
        for (int nt = 0; nt < 2; nt++)
#pragma unroll
            for (int kh = 0; kh < 2; kh++)
                bfr[nt][kh] = *(const v8s*)(Bc + (wn * 32 + nt * 16 + c) * 64
                                            + (((kh * 4 + quad) ^ c7) << 3));
        v8s af[4][2];
#pragma unroll
        for (int mt = 0; mt < 4; mt++)
#pragma unroll
            for (int kh = 0; kh < 2; kh++)
                af[mt][kh] = *(const v8s*)(Ac + (wm * 64 + mt * 16 + c) * 64
                                           + (((kh * 4 + quad) ^ c7) << 3));
        stageB(Bn, 0, ktn); stageB(Bn, 1, ktn); stageA(An, 0, ktn);
        asm volatile("s_barrier" ::: "memory");
        __builtin_amdgcn_s_setprio(1);
#pragma unroll
        for (int mt = 0; mt < 4; mt++)
#pragma unroll
            for (int nt = 0; nt < 2; nt++) {
                acc[mt][nt] = MM<SW>(af[mt][0], bfr[nt][0], acc[mt][nt]);
                acc[mt][nt] = MM<SW>(af[mt][1], bfr[nt][1], acc[mt][nt]);
            }
        __builtin_amdgcn_s_setprio(0);
        asm volatile("s_waitcnt vmcnt(3)" ::: "memory");
        asm volatile("s_barrier" ::: "memory");

#pragma unroll
        for (int mt = 0; mt < 4; mt++)
#pragma unroll
            for (int kh = 0; kh < 2; kh++)
                af[mt][kh] = *(const v8s*)(Ac + (128 + wm * 64 + mt * 16 + c) * 64
                                           + (((kh * 4 + quad) ^ c7) << 3));
        stageA(An, 1, ktn); stageA(An, 2, ktn); stageA(An, 3, ktn);
        asm volatile("s_barrier" ::: "memory");
        __builtin_amdgcn_s_setprio(1);
#pragma unroll
        for (int mt = 0; mt < 4; mt++)
#pragma unroll
            for (int nt = 0; nt < 2; nt++) {
                acc[4 + mt][nt] = MM<SW>(af[mt][0], bfr[nt][0], acc[4 + mt][nt]);
                acc[4 + mt][nt] = MM<SW>(af[mt][1], bfr[nt][1], acc[4 + mt][nt]);
            }
        __builtin_amdgcn_s_setprio(0);
        asm volatile("s_waitcnt vmcnt(2)" ::: "memory");
        asm volatile("s_barrier" ::: "memory");
    }
    asm volatile("s_waitcnt vmcnt(0)" ::: "memory");   // drain tail dummies
}

// ---------------------------------------------------------------------------
// QKV GEMM: C = xb(8192x1024) * wqkvT(3072x1024)^T, tile 256x128x64.
// Grid 768 = 32x24 (3 full rounds), bijective XCD swizzle. BN=128 makes the
// type (q/k/v) PURE per block (1024/128 = 8 blocks per type).
// V blocks run the operand-SWAPPED core: acc holds C^T, so the write to
// vt[bh][d][t] is 32B-contiguous along t (replaces transpose_v without the
// r4 scatter penalty).
// ---------------------------------------------------------------------------
__global__ __launch_bounds__(512, 2) void gemm_qkv(
    const bf16* __restrict__ A, const bf16* __restrict__ BT,
    const float* __restrict__ bq, const float* __restrict__ bk,
    const float* __restrict__ bv,
    bf16* __restrict__ qo, bf16* __restrict__ ko, bf16* __restrict__ vt)
{
    __shared__ __align__(16) bf16 As[2 * 256 * 64];   // 64 KB
    __shared__ __align__(16) bf16 Bs[2 * 128 * 64];   // 32 KB
    const int id  = blockIdx.x;
    const int fid = (id & 7) * 96 + (id >> 3);        // XCD-contiguous chunks
    const int by  = fid / 24, bx = fid - by * 24;     // bx fastest: share A
    const int m0  = by * 256, n0 = bx * 128;
    const int type = n0 >> 10;                        // 0=q 1=k 2=v (pure)

    v4f acc[8][2];
    if (type == 2) gemm_core_256x128<true >(A, BT, m0, n0, 1024, As, Bs, acc);
    else           gemm_core_256x128<false>(A, BT, m0, n0, 1024, As, Bs, acc);

    const int tid  = threadIdx.x;
    const int lane = tid & 63, wv = tid >> 6;
    const int quad = lane >> 4, c = lane & 15;
    const int wm = wv >> 2, wn = wv & 3;
    const int nbase = n0 & 1023;

    if (type < 2) {
        bf16* o = (type == 0) ? qo : ko;
        const float* bp = (type == 0) ? bq : bk;
        const float scale = (type == 0) ? QSCALE : 1.0f;
#pragma unroll
        for (int mt = 0; mt < 8; mt++)
#pragma unroll
            for (int nt = 0; nt < 2; nt++) {
                const int within = nbase + wn * 32 + nt * 16 + c;
                const int h = within >> 6, d = within & 63;
                const float bias = bp[within];
#pragma unroll
                for (int r = 0; r < 4; r++) {
                    const int row = m0 + wm * 128 + mt * 16 + quad * 4 + r;
                    const int b_ = row >> 11, t = row & 2047;
                    const int bh = b_ * HH + h;
                    o[((size_t)bh * TT + t) * HDIM + d] =
                        f2b((acc[mt][nt][r] + bias) * scale);
                }
            }
    } else {
        // SW epilogue: acc[mt][nt] = C^T fragment. Lane row (quad*4+r) = d
        // within the nt-frag; lane col c = t within the mt-frag. Stores are
        // 2B x 16 consecutive t = 32B runs.
        const int b_    = m0 >> 11;          // block never crosses batch
        const int m0loc = m0 & 2047;
#pragma unroll
        for (int mt = 0; mt < 8; mt++) {
            const int t = m0loc + wm * 128 + mt * 16 + c;
#pragma unroll
            for (int nt = 0; nt < 2; nt++)
#pragma unroll
                for (int r = 0; r < 4; r++) {
                    const int within = nbase + wn * 32 + nt * 16 + quad * 4 + r;
                    const int h = within >> 6, d = within & 63;
                    const int bh = b_ * HH + h;
                    vt[((size_t)bh * HDIM + d) * TT + t] =
                        f2b(acc[mt][nt][r] + bv[within]);
                }
        }
    }
}

// ---------------------------------------------------------------------------
// Output GEMM: out = ctx(8192x1024) * woT(1024x1024)^T + bo, fp32 out.
// Grid 256 = 32x8: exactly one block per CU.
// ---------------------------------------------------------------------------
__global__ __launch_bounds__(512, 2) void gemm_out(
    const bf16* __restrict__ A, const bf16* __restrict__ BT,
    const float* __restrict__ bo, float* __restrict__ out)
{
    __shared__ __align__(16) bf16 As[2 * 256 * 64];
    __shared__ __align__(16) bf16 Bs[2 * 128 * 64];
    const int id  = blockIdx.x;
    const int fid = (id & 7) * 32 + (id >> 3);
    const int by  = fid >> 3, bx = fid & 7;
    const int m0  = by * 256, n0 = bx * 128;

    v4f acc[8][2];
    gemm_core_256x128<false>(A, BT, m0, n0, 1024, As, Bs, acc);

    const int tid  = threadIdx.x;
    const int lane = tid & 63, wv = tid >> 6;
    const int quad = lane >> 4, c = lane & 15;
    const int wm = wv >> 2, wn = wv & 3;

#pragma unroll
    for (int mt = 0; mt < 8; mt++)
#pragma unroll
        for (int nt = 0; nt < 2; nt++) {
            const int col = n0 + wn * 32 + nt * 16 + c;
            const float bias = bo[col];
#pragma unroll
            for (int r = 0; r < 4; r++) {
                const int row = m0 + wm * 128 + mt * 16 + quad * 4 + r;
                out[(size_t)row * 1024 + col] = acc[mt][nt][r] + bias;
            }
        }
}

// ---------------------------------------------------------------------------
// Flash attention v8: r2's proven depth-1 pipeline (best measured) + T5
// setprio around each MFMA cluster (m191: +4-7% attn; multi-block/CU with
// phase-diverse waves is the regime where setprio pays).
// ---------------------------------------------------------------------------
__global__ __launch_bounds__(256, 4) void attn(
    const bf16* __restrict__ Q, const bf16* __restrict__ Kb,
    const bf16* __restrict__ VT, bf16* __restrict__ ctx,
    const int* __restrict__ bsp)
{
    __shared__ __align__(16) bf16 Kt[2][32 * 64];
    __shared__ __align__(16) bf16 Vt[2][64 * 32];
    __shared__ __align__(16) bf16 plds[4][2][16 * 32];

    const int bs = bsp[0];
    const float inv  = 1.0f / (float)bs;
    const float hinv = 0.5f * inv;
    const int tid = threadIdx.x, lane = tid & 63, wv = tid >> 6;
    const int quad = lane >> 4, c = lane & 15;
    const int bh = blockIdx.x & 63;
    const int j  = blockIdx.x >> 6;                // 0..15
    const int g_tbl[16] = {7,6,5,4, 0,1,2,3, 4,5,6,7, 3,2,1,0};
    const bool xt = j < 8;
    const int g  = g_tbl[j];
    const int q0g = (xt ? 0 : NN) + g * 128;

    const bf16* qp = Q  + (size_t)bh * TT * HDIM;
    const bf16* kp = Kb + (size_t)bh * TT * HDIM;
    const bf16* vp = VT + (size_t)bh * HDIM * TT;

    int d_lo = 0, nd = 0, nf = 0, b_lo = 0, nb = 0;
    if (xt) {
        d_lo = (bs * (q0g / bs)) & ~31;
        const int d_hi = min((bs * ((q0g + 127) / bs) + bs + 31) & ~31, NN);
        nd = (d_hi - d_lo) >> 5;
        const int f = bs * (q0g / bs);
        nf = f >> 5;
        b_lo = NN + (nf << 5);
        const int b_hi = NN + min((bs * ((q0g + 127) / bs) + 31) & ~31, NN);
        nb = (b_hi > b_lo) ? (b_hi - b_lo) >> 5 : 0;
    } else {
        const int q0l = q0g - NN;
        const int f = min(bs * (q0l / bs) + bs, NN);
        nf = f >> 5;
        b_lo = NN + (nf << 5);
        const int b_hi = NN + min((bs * ((q0l + 127) / bs) + bs + 31) & ~31, NN);
        nb = (b_hi > b_lo) ? (b_hi - b_lo) >> 5 : 0;
    }
    const int nc = nd + nf + nb;

    float bqv[2][4];
#pragma unroll
    for (int t = 0; t < 2; t++)
#pragma unroll
        for (int r = 0; r < 4; r++) {
            const int qrow = q0g + wv * 32 + t * 16 + quad * 4 + r;
            const int qloc = xt ? qrow : qrow - NN;
            bqv[t][r] = floorf(fmaf((float)qloc, inv, hinv));
        }

    v8s aq[2][2];
#pragma unroll
    for (int t = 0; t < 2; t++) {
        const int rowb = q0g + wv * 32 + t * 16;
        aq[t][0] = *(const v8s*)(qp + (size_t)(rowb + c) * HDIM + quad * 8);
        aq[t][1] = *(const v8s*)(qp + (size_t)(rowb + c) * HDIM + 32 + quad * 8);
    }

    v4f O[2][4];
#pragma unroll
    for (int t = 0; t < 2; t++)
#pragma unroll
        for (int dt = 0; dt < 4; dt++) O[t][dt] = (v4f){0.f, 0.f, 0.f, 0.f};
    float lr[2][4] = {{0.f,0.f,0.f,0.f},{0.f,0.f,0.f,0.f}};

    const int klrow = lane >> 3, ks8 = lane & 7;
    const bf16* kSrc0 = kp + (size_t)(wv * 8 + klrow) * HDIM + ((ks8 ^ klrow) << 3);
    const int vlrow = lane >> 2, vs8 = lane & 3;
    const bf16* vSrc0 = vp + (size_t)(wv * 16 + vlrow) * TT + ((vs8 ^ (vlrow & 3)) << 3);

    auto kb_of = [&](int i, int& kb, int& type) {
        if (i < nd)           { kb = d_lo + (i << 5);             type = 1; }
        else if (i < nd + nf) { kb = NN + ((i - nd) << 5);        type = 0; }
        else                  { kb = b_lo + ((i - nd - nf) << 5); type = xt ? 2 : 3; }
    };
    auto stage = [&](int i) {
        int kb, ty; kb_of(i, kb, ty);
        const int sel = i & 1;
        GLDS16(&Kt[sel][wv * 512], kSrc0 + (size_t)kb * HDIM);
        GLDS16(&Vt[sel][wv * 512], vSrc0 + kb);
    };

    stage(0);
    asm volatile("s_waitcnt vmcnt(0)" ::: "memory");
    asm volatile("s_barrier" ::: "memory");

    const int xk = c & 7, xv = c & 3;
    const int pquad = quad << 3;
#pragma unroll 1
    for (int i = 0; i < nc; i++) {
        int kb, type; kb_of(i, kb, type);
        const int sel = i & 1;
        const bf16* Kl = Kt[sel];
        const bf16* Vl = Vt[sel];

        const v8s k0a = *(const v8s*)(Kl + c * 64        + ((quad       ^ xk) << 3));
        const v8s k0b = *(const v8s*)(Kl + c * 64        + (((quad ^ 4) ^ xk) << 3));
        const v8s k1a = *(const v8s*)(Kl + (16 + c) * 64 + ((quad       ^ xk) << 3));
        const v8s k1b = *(const v8s*)(Kl + (16 + c) * 64 + (((quad ^ 4) ^ xk) << 3));
        v8s vf[4];
#pragma unroll
        for (int dt = 0; dt < 4; dt++)
            vf[dt] = *(const v8s*)(Vl + (dt * 16 + c) * 32 + ((quad ^ xv) << 3));

        if (i + 1 < nc) stage(i + 1);

        float bkA = 0.f, bkB = 0.f;
        if (type) {
            const int off = (type == 1) ? 0 : NN;
            bkA = floorf(fmaf((float)(kb + c - off),      inv, hinv));
            bkB = floorf(fmaf((float)(kb + 16 + c - off), inv, hinv));
        }

#pragma unroll
        for (int t = 0; t < 2; t++) {
            v4f Sa = (v4f){0.f, 0.f, 0.f, 0.f};
            v4f Sb = (v4f){0.f, 0.f, 0.f, 0.f};
            __builtin_amdgcn_s_setprio(1);
            Sa = mfma16x16x32(aq[t][0], k0a, Sa);
            Sa = mfma16x16x32(aq[t][1], k0b, Sa);
            Sb = mfma16x16x32(aq[t][0], k1a, Sb);
            Sb = mfma16x16x32(aq[t][1], k1b, Sb);
            __builtin_amdgcn_s_setprio(0);
            bf16* pw = &plds[wv][t][(quad * 4) * 32];
#pragma unroll
            for (int r = 0; r < 4; r++) {
                float sa = Sa[r], sb = Sb[r];
                if (type == 1) {
                    if (bkA != bqv[t][r]) sa = MASKV;
                    if (bkB != bqv[t][r]) sb = MASKV;
                } else if (type == 2) {
                    if (!(bkA < bqv[t][r])) sa = MASKV;
                    if (!(bkB < bqv[t][r])) sb = MASKV;
                } else if (type == 3) {
                    if (!(bkA <= bqv[t][r])) sa = MASKV;
                    if (!(bkB <= bqv[t][r])) sb = MASKV;
                }
                const float pa = EXP2F(sa);
                const float pb = EXP2F(sb);
                lr[t][r] += pa + pb;
                pw[r * 32 + (c ^ pquad)]        = f2b(pa);
                pw[r * 32 + ((c + 16) ^ pquad)] = f2b(pb);
            }
        }
        asm volatile("s_waitcnt lgkmcnt(0)" ::: "memory");
#pragma unroll
        for (int t = 0; t < 2; t++) {
            const v8s pf = *(const v8s*)(&plds[wv][t][c * 32 +
                                        ((quad ^ ((c >> 2) & 3)) << 3)]);
            __builtin_amdgcn_s_setprio(1);
#pragma unroll
            for (int dt = 0; dt < 4; dt++)
                O[t][dt] = mfma16x16x32(pf, vf[dt], O[t][dt]);
            __builtin_amdgcn_s_setprio(0);
        }

        asm volatile("s_waitcnt vmcnt(0)" ::: "memory");
        asm volatile("s_barrier" ::: "memory");
    }

    const int b_ = bh >> 4, h = bh & 15;
#pragma unroll
    for (int t = 0; t < 2; t++)
#pragma unroll
        for (int r = 0; r < 4; r++) {
            float s = lr[t][r];
#pragma unroll
            for (int off = 1; off < 16; off <<= 1) s += __shfl_xor(s, off);
            const float invl = 1.0f / fmaxf(s, 1e-30f);
            const int trow = q0g + wv * 32 + t * 16 + quad * 4 + r;
#pragma unroll
            for (int dt = 0; dt < 4; dt++)
                ctx[((size_t)(b_ * TT + trow)) * DD + h * 64 + dt * 16 + c] =
                    f2b(O[t][dt][r] * invl);
        }
}

// ---------------------------------------------------------------------------
extern "C" void kernel_launch(void* const* d_in, const int* in_sizes, int n_in,
                              void* d_out, int out_size, void* d_ws, size_t ws_size,
                              hipStream_t stream)
{
    const float* x  = (const float*)d_in[0];
    const float* Wq = (const float*)d_in[1];
    const float* bq = (const float*)d_in[2];
    const float* Wk = (const float*)d_in[3];
    const float* bk = (const float*)d_in[4];
    const float* Wv = (const float*)d_in[5];
    const float* bv = (const float*)d_in[6];
    const float* Wo = (const float*)d_in[7];
    const float* bo = (const float*)d_in[8];
    const int*  bsp = (const int*)d_in[9];
    float* out = (float*)d_out;

    bf16* ws    = (bf16*)d_ws;
    bf16* xb    = ws;                           // reused as ctx after gemm_qkv
    bf16* wqkvT = xb + 8388608;
    bf16* woT   = wqkvT + 3 * 1024 * 1024;
    bf16* qbuf  = woT + 1024 * 1024;            // (bh,t,d)
    bf16* kbuf  = qbuf + 8388608;
    bf16* vt    = kbuf + 8388608;               // (bh,d,t) written by gemm_qkv
    bf16* ctx   = xb;

    cast_x<<<8192, 256, 0, stream>>>(x, xb);
    transpose_w<<<dim3(16, 16, 4), dim3(64, 4), 0, stream>>>(Wq, Wk, Wv, Wo, wqkvT);
    gemm_qkv<<<768, 512, 0, stream>>>(xb, wqkvT, bq, bk, bv, qbuf, kbuf, vt);
    attn<<<1024, 256, 0, stream>>>(qbuf, kbuf, vt, ctx, bsp);
    gemm_out<<<256, 512, 0, stream>>>(ctx, woT, bo, out);
}